// Round 6
// baseline (111.877 us; speedup 1.0000x reference)
//
#include <hip/hip_runtime.h>
#include <hip/hip_bf16.h>
#include <math.h>

typedef __attribute__((ext_vector_type(8))) short short8v;
typedef __attribute__((ext_vector_type(4))) float f32x4;

// ---------------- ws layout ----------------
// float region (offsets in floats):
#define F_S1 0
#define F_H1 32
#define F_S2 64          // 64 slots
#define F_H2 128         // 64 slots
#define F_S3 192         // 128 slots
#define F_H3 320         // 128 slots
#define F_S4 448         // 256 slots
#define F_H4 704         // 256 slots
#define F_B1 960         // 32 slots
#define F_END 1024
// bf16 region (offsets in bf16 units):
#define H_BASE (F_END*2)
#define H_P1  H_BASE                    // 128 samples * 256*32 (pre-swizzled [t][c])
#define H_WA1 (H_P1 + 128*8192)         // 32*640
#define H_WA2 (H_WA1 + 32*640)          // 64*320
#define H_WA3 (H_WA2 + 64*320)          // 112*640
#define H_WA4 (H_WA3 + 112*640)         // 208*1280

#define N_WA1 (32*640)
#define N_WA2 (64*320)
#define N_WA3 (112*640)
#define N_WA4 (208*1280)
#define N_WTOT (N_WA1 + N_WA2 + N_WA3 + N_WA4)

__device__ __forceinline__ float eluf(float v) {
    return v > 0.f ? v : (expf(v) - 1.f);
}
__device__ __forceinline__ float ldh(const __hip_bfloat16* p) { return __bfloat162float(*p); }

__device__ __forceinline__ void ld4f(const float* p, float* v) {
    float2 a = *(const float2*)p, c = *(const float2*)(p + 2);
    v[0] = a.x; v[1] = a.y; v[2] = c.x; v[3] = c.y;
}

// ---------------- K0: precompute bf16 k-major weights + BN affines ----------------
__global__ __launch_bounds__(256) void k_pre2(
    const float* __restrict__ ct_w, const float* __restrict__ ct_b,
    const float* __restrict__ cs_w,
    const float* __restrict__ g1, const float* __restrict__ b1,
    const float* __restrict__ m1, const float* __restrict__ v1,
    const float* __restrict__ w2,
    const float* __restrict__ g2, const float* __restrict__ b2,
    const float* __restrict__ m2, const float* __restrict__ v2,
    const float* __restrict__ w3,
    const float* __restrict__ g3, const float* __restrict__ b3,
    const float* __restrict__ m3, const float* __restrict__ v3,
    const float* __restrict__ w4,
    const float* __restrict__ g4, const float* __restrict__ b4,
    const float* __restrict__ m4, const float* __restrict__ v4,
    float* __restrict__ ws) {
    __hip_bfloat16* wsh = (__hip_bfloat16*)ws;
    int t = blockIdx.x * 256 + threadIdx.x;
    if (t < N_WA1) {
        int o = t / 640, kv = t - o * 640, kk = kv / 64, c = kv - kk * 64;
        float s = 0.f;
        if (o < 25)
            for (int i = 0; i < 25; ++i)
                s += cs_w[(o * 25 + i) * 64 + c] * ct_w[i * 10 + kk];
        wsh[H_WA1 + t] = __float2bfloat16(s);
    } else if (t < N_WA1 + N_WA2) {
        int u = t - N_WA1;
        int o = u / 320, kv = u - o * 320, kk = kv / 32, c = kv - kk * 32;
        float s = (o < 50 && c < 25) ? w2[(o * 25 + c) * 10 + kk] : 0.f;
        wsh[H_WA2 + u] = __float2bfloat16(s);
    } else if (t < N_WA1 + N_WA2 + N_WA3) {
        int u = t - N_WA1 - N_WA2;
        int o = u / 640, kv = u - o * 640, kk = kv / 64, c = kv - kk * 64;
        float s = (o < 100 && c < 50) ? w3[(o * 50 + c) * 10 + kk] : 0.f;
        wsh[H_WA3 + u] = __float2bfloat16(s);
    } else if (t < N_WTOT) {
        int u = t - N_WA1 - N_WA2 - N_WA3;
        int o = u / 1280, kv = u - o * 1280, kk = kv / 128, c = kv - kk * 128;
        float s = (o < 200 && c < 100) ? w4[(o * 100 + c) * 10 + kk] : 0.f;
        wsh[H_WA4 + u] = __float2bfloat16(s);
    } else {
        int j = t - N_WTOT;
        if (j < 25) {
            float sc = g1[j] / sqrtf(v1[j] + 1e-5f);
            ws[F_S1 + j] = sc; ws[F_H1 + j] = b1[j] - m1[j] * sc;
        } else if (j >= 32 && j < 82) {
            int ch = j - 32;
            float sc = g2[ch] / sqrtf(v2[ch] + 1e-5f);
            ws[F_S2 + ch] = sc; ws[F_H2 + ch] = b2[ch] - m2[ch] * sc;
        } else if (j >= 96 && j < 196) {
            int ch = j - 96;
            float sc = g3[ch] / sqrtf(v3[ch] + 1e-5f);
            ws[F_S3 + ch] = sc; ws[F_H3 + ch] = b3[ch] - m3[ch] * sc;
        } else if (j >= 224 && j < 424) {
            int ch = j - 224;
            float sc = g4[ch] / sqrtf(v4[ch] + 1e-5f);
            ws[F_S4 + ch] = sc; ws[F_H4 + ch] = b4[ch] - m4[ch] * sc;
        } else if (j >= 448 && j < 473) {
            int o = j - 448;
            float s = 0.f;
            for (int i = 0; i < 25; ++i) {
                float cs = 0.f;
                for (int c = 0; c < 64; ++c) cs += cs_w[(o * 25 + i) * 64 + c];
                s += cs * ct_b[i];
            }
            ws[F_B1 + o] = s;
        }
    }
}

// ---------------- shared MFMA item helper ----------------
// Computes one 16x16 output tile column-block: acc over K = 32*NS,
// A row base Wrow (k-major), B from LDS xb [t][CINP] swizzled.
template<int NS, int CB, int CINP>
__device__ __forceinline__ f32x4 conv_item(
    const __hip_bfloat16* __restrict__ Wrow,
    const __hip_bfloat16* xb, int lo, int kg, int rowBase) {
    constexpr int SWM = (CINP >= 64) ? 7 : 3;
    const short8v* Ap = (const short8v*)Wrow;
    f32x4 acc = {0.f, 0.f, 0.f, 0.f};
#pragma unroll 1
    for (int sb = 0; sb < NS; sb += 10) {
        short8v af[10];
#pragma unroll
        for (int u = 0; u < 10; ++u) af[u] = Ap[(sb + u) * 4 + kg];
#pragma unroll
        for (int u = 0; u < 10; ++u) {
            int s = sb + u;
            int kk = s / CB, cb = s % CB;
            int r = rowBase + lo + kk;
            int cs = (cb * 32 + kg * 8) ^ (8 * (r & SWM));
            short8v bf = *(const short8v*)&xb[r * CINP + cs];
            acc = __builtin_amdgcn_mfma_f32_16x16x32_bf16(af[u], bf, acc, 0, 0, 0);
        }
    }
    return acc;
}

// ---------------- K1: fused conv1 + BN1 + ELU + pool3 ----------------
// grid (6, 128), 256 thr. PT=42 pooled/tile. Output p1 pre-transposed
// [t][c] bf16, swizzled (c ^ 8*(t&3)), rows 256 (pad zero), 32 c.
__global__ __launch_bounds__(256) void k_conv1(
    const float* __restrict__ x, float* __restrict__ ws) {
    __hip_bfloat16* wsh = (__hip_bfloat16*)ws;
    const __hip_bfloat16* Wa = wsh + H_WA1;
    int bx = blockIdx.x, b = blockIdx.y;
    int tp0 = bx * 42;
    int PTb = min(42, 247 - tp0);
    int t0 = 126 * bx;

    __shared__ __align__(16) __hip_bfloat16 xb[144 * 64];   // [t][c] swizzled
    __shared__ __align__(16) __hip_bfloat16 eb[32 * 128];   // post-ELU, pre-pool

    // stage x: 144 rows x 64 ch, transposed, bf16, swizzled
    for (int f = threadIdx.x; f < 64 * 36; f += 256) {
        int c = f / 36, j = f - c * 36;
        int t = t0 + 4 * j;
        const float* src = x + ((size_t)b * 64 + c) * 750 + t;
        float v[4];
        if (t + 3 < 750) {
            ld4f(src, v);
        } else {
#pragma unroll
            for (int e = 0; e < 4; ++e) v[e] = (t + e < 750) ? src[e] : 0.f;
        }
#pragma unroll
        for (int e = 0; e < 4; ++e) {
            int r = 4 * j + e;
            xb[r * 64 + (c ^ (8 * (r & 7)))] = __float2bfloat16(v[e]);
        }
    }
    __syncthreads();

    // MFMA: 4 waves -> (ot, ctg); NOT=2, CSPLIT=2, CTW=4, NS=20 (CB=2)
    int lane = threadIdx.x & 63, wid = threadIdx.x >> 6;
    int lo = lane & 15, kg = lane >> 4;
    int ot = wid >> 1, ctg = wid & 1;
    const short8v* Ap = (const short8v*)(Wa + (size_t)(ot * 16 + lo) * 640);
    f32x4 acc[4];
#pragma unroll
    for (int q = 0; q < 4; ++q) acc[q] = (f32x4){0.f, 0.f, 0.f, 0.f};
#pragma unroll 1
    for (int sb = 0; sb < 20; sb += 10) {
        short8v af[10];
#pragma unroll
        for (int u = 0; u < 10; ++u) af[u] = Ap[(sb + u) * 4 + kg];
#pragma unroll
        for (int u = 0; u < 10; ++u) {
            int s = sb + u;
            int kk = s >> 1, cb = s & 1;
#pragma unroll
            for (int q = 0; q < 4; ++q) {
                int r = (ctg * 4 + q) * 16 + lo + kk;
                int cs = (cb * 32 + kg * 8) ^ (8 * (r & 7));
                short8v bf = *(const short8v*)&xb[r * 64 + cs];
                acc[q] = __builtin_amdgcn_mfma_f32_16x16x32_bf16(af[u], bf, acc[q], 0, 0, 0);
            }
        }
    }
#pragma unroll
    for (int q = 0; q < 4; ++q) {
        int tloc = (ctg * 4 + q) * 16 + lo;
#pragma unroll
        for (int e = 0; e < 4; ++e) {
            int o2 = ot * 16 + kg * 4 + e;      // < 32
            float a = acc[q][e] + ws[F_B1 + o2];
            eb[o2 * 128 + tloc] = __float2bfloat16(eluf(a * ws[F_S1 + o2] + ws[F_H1 + o2]));
        }
    }
    __syncthreads();

    // pool + pre-swizzled transposed store (zeros for c>=25)
    __hip_bfloat16* p1g = wsh + H_P1 + (size_t)b * 8192;
    for (int i = threadIdx.x; i < 32 * 42; i += 256) {
        int o = i / 42, pl = i - o * 42;
        if (pl < PTb) {
            int tp = tp0 + pl;
            float val = 0.f;
            if (o < 25) {
                const __hip_bfloat16* ep = eb + o * 128 + 3 * pl;
                val = fmaxf(fmaxf(ldh(ep), ldh(ep + 1)), ldh(ep + 2));
            }
            p1g[tp * 32 + (o ^ (8 * (tp & 3)))] = __float2bfloat16(val);
        }
    }
    if (bx == 5) {  // zero pad rows 247..255
        for (int i = threadIdx.x; i < 9 * 32; i += 256) {
            int r = 247 + i / 32, c = i & 31;
            p1g[r * 32 + c] = __float2bfloat16(0.f);
        }
    }
}

// ---------------- K2: fused tail — L2+L3+L4+fc+heads, one sample/block ----------------
__global__ __launch_bounds__(512) void k_tail(
    const float* __restrict__ ws,
    const float* __restrict__ fcw, const float* __restrict__ fcb,
    const int* __restrict__ cids,
    const float* __restrict__ hW1, const float* __restrict__ hb1,
    const float* __restrict__ hW2, const float* __restrict__ hb2,
    float* __restrict__ out) {
    const __hip_bfloat16* wsh = (const __hip_bfloat16*)ws;
    const __hip_bfloat16* wa2 = wsh + H_WA2;
    const __hip_bfloat16* wa3 = wsh + H_WA3;
    const __hip_bfloat16* wa4 = wsh + H_WA4;
    int b = blockIdx.x;
    int tid = threadIdx.x;
    int lane = tid & 63, wid = tid >> 6;
    int lo = lane & 15, kg = lane >> 4;

    __shared__ __align__(16) __hip_bfloat16 p1s[256 * 32];   // 16 KB = 1024 uint4
    __shared__ __align__(16) __hip_bfloat16 p2s[96 * 64];    // 12 KB
    __shared__ __align__(16) __hip_bfloat16 p3s[32 * 128];   // 8 KB
    __shared__ __align__(16) __hip_bfloat16 ebh[112 * 80];   // 17.5 KB scratch
    __shared__ float p4s[200 * 4];
    __shared__ float red[4][128];
    __shared__ float fsf[4];

    // ---- stage p1 (vector copy; already transposed+swizzled) + zero p2s/p3s ----
    {
        const uint4* src = (const uint4*)(wsh + H_P1 + (size_t)b * 8192);
        uint4* dst = (uint4*)p1s;
        dst[tid] = src[tid];                 // p1s = 1024 uint4: 2 per thread
        dst[tid + 512] = src[tid + 512];
        uint4 z = {0, 0, 0, 0};
        ((uint4*)p2s)[tid] = z;              // p2s: 768 uint4
        if (tid < 256) ((uint4*)p2s)[512 + tid] = z;
        ((uint4*)p3s)[tid] = z;              // p3s: 512 uint4
    }
    __syncthreads();

    // ---- L2: 25->50, K=320, 4 t-chunks of 20 pooled ----
    for (int c0 = 0; c0 < 4; ++c0) {
        int tb = 60 * c0;
        int PTb = (c0 == 3) ? 19 : 20;
        for (int it = wid; it < 16; it += 8) {
            int ot = it >> 2, ct = it & 3;
            f32x4 a = conv_item<10, 1, 32>(wa2 + (size_t)(ot * 16 + lo) * 320,
                                           p1s, lo, kg, tb + ct * 16);
            int tloc = ct * 16 + lo;
#pragma unroll
            for (int e = 0; e < 4; ++e) {
                int o2 = ot * 16 + kg * 4 + e;  // < 64
                ebh[o2 * 64 + tloc] =
                    __float2bfloat16(eluf(a[e] * ws[F_S2 + o2] + ws[F_H2 + o2]));
            }
        }
        __syncthreads();
        for (int i = tid; i < 50 * 20; i += 512) {
            int o = i / 20, pl = i - o * 20;
            if (pl < PTb) {
                int tp = 20 * c0 + pl;
                const __hip_bfloat16* ep = ebh + o * 64 + 3 * pl;
                float m = fmaxf(fmaxf(ldh(ep), ldh(ep + 1)), ldh(ep + 2));
                p2s[tp * 64 + (o ^ (8 * (tp & 7)))] = __float2bfloat16(m);
            }
        }
        __syncthreads();
    }

    // ---- L3: 50->100, K=640 ----
    for (int it = wid; it < 35; it += 8) {
        int ot = it / 5, ct = it - 5 * ot;
        f32x4 a = conv_item<20, 2, 64>(wa3 + (size_t)(ot * 16 + lo) * 640,
                                       p2s, lo, kg, ct * 16);
        int tloc = ct * 16 + lo;
#pragma unroll
        for (int e = 0; e < 4; ++e) {
            int o2 = ot * 16 + kg * 4 + e;      // < 112
            ebh[o2 * 80 + tloc] =
                __float2bfloat16(eluf(a[e] * ws[F_S3 + o2] + ws[F_H3 + o2]));
        }
    }
    __syncthreads();
    for (int i = tid; i < 100 * 23; i += 512) {
        int o = i / 23, pl = i - 23 * o;
        const __hip_bfloat16* ep = ebh + o * 80 + 3 * pl;
        float m = fmaxf(fmaxf(ldh(ep), ldh(ep + 1)), ldh(ep + 2));
        p3s[pl * 128 + (o ^ (8 * (pl & 7)))] = __float2bfloat16(m);
    }
    __syncthreads();

    // ---- L4: 100->200, K=1280 ----
    for (int it = wid; it < 13; it += 8) {
        int ot = it;
        f32x4 a = conv_item<40, 4, 128>(wa4 + (size_t)(ot * 16 + lo) * 1280,
                                        p3s, lo, kg, 0);
#pragma unroll
        for (int e = 0; e < 4; ++e) {
            int o2 = ot * 16 + kg * 4 + e;      // < 208
            ebh[o2 * 16 + lo] =
                __float2bfloat16(eluf(a[e] * ws[F_S4 + o2] + ws[F_H4 + o2]));
        }
    }
    __syncthreads();
    for (int i = tid; i < 800; i += 512) {
        int o = i >> 2, pl = i & 3;
        const __hip_bfloat16* ep = ebh + o * 16 + 3 * pl;
        p4s[o * 4 + pl] = fmaxf(fmaxf(ldh(ep), ldh(ep + 1)), ldh(ep + 2));
    }
    __syncthreads();

    // ---- fc + MoE head ----
    int j = tid;
    if (j < 128) {
        float pa[4] = {0.f, 0.f, 0.f, 0.f};
        for (int c = j; c < 200; c += 128) {
            const float* pp = p4s + c * 4;
            float v0 = pp[0], v1 = pp[1], v2 = pp[2], v3 = pp[3];
#pragma unroll
            for (int o = 0; o < 4; ++o) {
                const float* fw = fcw + (o * 200 + c) * 4;
                pa[o] += fw[0] * v0 + fw[1] * v1 + fw[2] * v2 + fw[3] * v3;
            }
        }
#pragma unroll
        for (int o = 0; o < 4; ++o) red[o][j] = pa[o];
    }
    __syncthreads();
    for (int s = 64; s > 0; s >>= 1) {
        if (j < s) {
#pragma unroll
            for (int o = 0; o < 4; ++o) red[o][j] += red[o][j + s];
        }
        __syncthreads();
    }
    if (j < 4) fsf[j] = red[j][0] + fcb[j];
    __syncthreads();

    int cid = cids[b];
    if (j < 128) {
        float hvv = hb1[cid * 128 + j];
#pragma unroll
        for (int f = 0; f < 4; ++f) hvv += fsf[f] * hW1[(cid * 4 + f) * 128 + j];
        hvv = fmaxf(hvv, 0.f);
#pragma unroll
        for (int o = 0; o < 4; ++o) red[o][j] = hvv * hW2[(cid * 128 + j) * 4 + o];
    }
    __syncthreads();
    for (int s = 64; s > 0; s >>= 1) {
        if (j < s) {
#pragma unroll
            for (int o = 0; o < 4; ++o) red[o][j] += red[o][j + s];
        }
        __syncthreads();
    }
    if (j < 4) out[b * 4 + j] = red[j][0] + hb2[cid * 4 + j];
}

// ---------------- launch ----------------
extern "C" void kernel_launch(void* const* d_in, const int* in_sizes, int n_in,
                              void* d_out, int out_size, void* d_ws, size_t ws_size,
                              hipStream_t stream) {
    (void)in_sizes; (void)n_in; (void)out_size; (void)ws_size;
    const float* x    = (const float*)d_in[0];
    const int*   cid  = (const int*)d_in[1];
    const float* ctw  = (const float*)d_in[2];
    const float* ctb  = (const float*)d_in[3];
    const float* csw  = (const float*)d_in[4];
    const float* g1 = (const float*)d_in[5],  *b1 = (const float*)d_in[6];
    const float* m1 = (const float*)d_in[7],  *v1 = (const float*)d_in[8];
    const float* w2 = (const float*)d_in[9];
    const float* g2 = (const float*)d_in[10], *b2 = (const float*)d_in[11];
    const float* m2 = (const float*)d_in[12], *v2 = (const float*)d_in[13];
    const float* w3 = (const float*)d_in[14];
    const float* g3 = (const float*)d_in[15], *b3 = (const float*)d_in[16];
    const float* m3 = (const float*)d_in[17], *v3 = (const float*)d_in[18];
    const float* w4 = (const float*)d_in[19];
    const float* g4 = (const float*)d_in[20], *b4 = (const float*)d_in[21];
    const float* m4 = (const float*)d_in[22], *v4 = (const float*)d_in[23];
    const float* fcw = (const float*)d_in[24], *fcb = (const float*)d_in[25];
    const float* hW1 = (const float*)d_in[26], *hb1 = (const float*)d_in[27];
    const float* hW2 = (const float*)d_in[28], *hb2 = (const float*)d_in[29];
    float* ws  = (float*)d_ws;
    float* out = (float*)d_out;

    k_pre2<<<dim3((N_WTOT + 512 + 255) / 256), dim3(256), 0, stream>>>(
        ctw, ctb, csw, g1, b1, m1, v1, w2, g2, b2, m2, v2,
        w3, g3, b3, m3, v3, w4, g4, b4, m4, v4, ws);
    k_conv1<<<dim3(6, 128), dim3(256), 0, stream>>>(x, ws);
    k_tail<<<dim3(128), dim3(512), 0, stream>>>(ws, fcw, fcb, cid,
                                                hW1, hb1, hW2, hb2, out);
}

// Round 7
// 95.928 us; speedup vs baseline: 1.1663x; 1.1663x over previous
//
#include <hip/hip_runtime.h>
#include <hip/hip_bf16.h>
#include <math.h>

typedef __attribute__((ext_vector_type(8))) short short8v;
typedef __attribute__((ext_vector_type(4))) float f32x4;

// ---------------- ws layout ----------------
// float region (offsets in floats):
#define F_S1 0
#define F_H1 32
#define F_S2 64          // 64 slots
#define F_H2 128         // 64 slots
#define F_S3 192         // 128 slots
#define F_H3 320         // 128 slots
#define F_S4 448         // 256 slots
#define F_H4 704         // 256 slots
#define F_B1 960         // 32 slots
#define F_P4 1024        // 128*200*4 floats
#define F_END (1024 + 128*200*4)
// bf16 region (offsets in bf16 units):
#define H_BASE (F_END*2)
#define H_P1  H_BASE                    // [t=256][s=128][c=32]  (t<247 written)
#define H_WA1 (H_P1 + 128*8192)         // 32*640   (o, kk*64+c)
#define H_WA2 (H_WA1 + 32*640)          // 64*320   (o, kk*32+c)
#define H_WA3 (H_WA2 + 64*320)          // 112*640  (o, kk*64+c)
#define H_WA4 (H_WA3 + 112*640)         // 208*1280 (o, kk*128+c)
#define H_P2  (H_WA4 + 208*1280)        // [t=79][s=128][c=64]
#define H_P3  (H_P2 + 79*128*64)        // [t=23][s=128][c=128]

#define N_WA1 (32*640)
#define N_WA2 (64*320)
#define N_WA3 (112*640)
#define N_WA4 (208*1280)
#define N_WTOT (N_WA1 + N_WA2 + N_WA3 + N_WA4)

__device__ __forceinline__ float eluf(float v) {
    return v > 0.f ? v : (expf(v) - 1.f);
}
__device__ __forceinline__ float ldh(const __hip_bfloat16* p) { return __bfloat162float(*p); }
__device__ __forceinline__ unsigned short bfb(float v) {
    __hip_bfloat16 h = __float2bfloat16(v);
    return reinterpret_cast<unsigned short&>(h);
}
__device__ __forceinline__ void ld4f(const float* p, float* v) {
    float2 a = *(const float2*)p, c = *(const float2*)(p + 2);
    v[0] = a.x; v[1] = a.y; v[2] = c.x; v[3] = c.y;
}

// ---------------- K0: precompute bf16 k-major weights + BN affines ----------------
__global__ __launch_bounds__(256) void k_pre2(
    const float* __restrict__ ct_w, const float* __restrict__ ct_b,
    const float* __restrict__ cs_w,
    const float* __restrict__ g1, const float* __restrict__ b1,
    const float* __restrict__ m1, const float* __restrict__ v1,
    const float* __restrict__ w2,
    const float* __restrict__ g2, const float* __restrict__ b2,
    const float* __restrict__ m2, const float* __restrict__ v2,
    const float* __restrict__ w3,
    const float* __restrict__ g3, const float* __restrict__ b3,
    const float* __restrict__ m3, const float* __restrict__ v3,
    const float* __restrict__ w4,
    const float* __restrict__ g4, const float* __restrict__ b4,
    const float* __restrict__ m4, const float* __restrict__ v4,
    float* __restrict__ ws) {
    __hip_bfloat16* wsh = (__hip_bfloat16*)ws;
    int t = blockIdx.x * 256 + threadIdx.x;
    if (t < N_WA1) {
        int o = t / 640, kv = t - o * 640, kk = kv / 64, c = kv - kk * 64;
        float s = 0.f;
        if (o < 25)
            for (int i = 0; i < 25; ++i)
                s += cs_w[(o * 25 + i) * 64 + c] * ct_w[i * 10 + kk];
        wsh[H_WA1 + t] = __float2bfloat16(s);
    } else if (t < N_WA1 + N_WA2) {
        int u = t - N_WA1;
        int o = u / 320, kv = u - o * 320, kk = kv / 32, c = kv - kk * 32;
        float s = (o < 50 && c < 25) ? w2[(o * 25 + c) * 10 + kk] : 0.f;
        wsh[H_WA2 + u] = __float2bfloat16(s);
    } else if (t < N_WA1 + N_WA2 + N_WA3) {
        int u = t - N_WA1 - N_WA2;
        int o = u / 640, kv = u - o * 640, kk = kv / 64, c = kv - kk * 64;
        float s = (o < 100 && c < 50) ? w3[(o * 50 + c) * 10 + kk] : 0.f;
        wsh[H_WA3 + u] = __float2bfloat16(s);
    } else if (t < N_WTOT) {
        int u = t - N_WA1 - N_WA2 - N_WA3;
        int o = u / 1280, kv = u - o * 1280, kk = kv / 128, c = kv - kk * 128;
        float s = (o < 200 && c < 100) ? w4[(o * 100 + c) * 10 + kk] : 0.f;
        wsh[H_WA4 + u] = __float2bfloat16(s);
    } else {
        int j = t - N_WTOT;
        if (j < 25) {
            float sc = g1[j] / sqrtf(v1[j] + 1e-5f);
            ws[F_S1 + j] = sc; ws[F_H1 + j] = b1[j] - m1[j] * sc;
        } else if (j >= 32 && j < 82) {
            int ch = j - 32;
            float sc = g2[ch] / sqrtf(v2[ch] + 1e-5f);
            ws[F_S2 + ch] = sc; ws[F_H2 + ch] = b2[ch] - m2[ch] * sc;
        } else if (j >= 96 && j < 196) {
            int ch = j - 96;
            float sc = g3[ch] / sqrtf(v3[ch] + 1e-5f);
            ws[F_S3 + ch] = sc; ws[F_H3 + ch] = b3[ch] - m3[ch] * sc;
        } else if (j >= 224 && j < 424) {
            int ch = j - 224;
            float sc = g4[ch] / sqrtf(v4[ch] + 1e-5f);
            ws[F_S4 + ch] = sc; ws[F_H4 + ch] = b4[ch] - m4[ch] * sc;
        } else if (j >= 448 && j < 473) {
            int o = j - 448;
            float s = 0.f;
            for (int i = 0; i < 25; ++i) {
                float cs = 0.f;
                for (int c = 0; c < 64; ++c) cs += cs_w[(o * 25 + i) * 64 + c];
                s += cs * ct_b[i];
            }
            ws[F_B1 + o] = s;
        }
    }
}

// ---------------- K1: fused conv1 + BN1 + ELU + pool3 ----------------
// grid (6, 128), 256 thr. Output p1 as [t][s][32] bf16 (c>=25 zero).
__global__ __launch_bounds__(256) void k_conv1(
    const float* __restrict__ x, float* __restrict__ ws) {
    __hip_bfloat16* wsh = (__hip_bfloat16*)ws;
    const __hip_bfloat16* Wa = wsh + H_WA1;
    int bx = blockIdx.x, b = blockIdx.y;
    int tp0 = bx * 42;
    int PTb = min(42, 247 - tp0);
    int t0 = 126 * bx;

    __shared__ __align__(16) __hip_bfloat16 xb[144 * 64];   // [t][c] swizzled
    __shared__ __align__(16) __hip_bfloat16 eb[32 * 128];   // post-ELU, pre-pool

    for (int f = threadIdx.x; f < 64 * 36; f += 256) {
        int c = f / 36, j = f - c * 36;
        int t = t0 + 4 * j;
        const float* src = x + ((size_t)b * 64 + c) * 750 + t;
        float v[4];
        if (t + 3 < 750) {
            ld4f(src, v);
        } else {
#pragma unroll
            for (int e = 0; e < 4; ++e) v[e] = (t + e < 750) ? src[e] : 0.f;
        }
#pragma unroll
        for (int e = 0; e < 4; ++e) {
            int r = 4 * j + e;
            xb[r * 64 + (c ^ (8 * (r & 7)))] = __float2bfloat16(v[e]);
        }
    }
    __syncthreads();

    int lane = threadIdx.x & 63, wid = threadIdx.x >> 6;
    int lo = lane & 15, kg = lane >> 4;
    int ot = wid >> 1, ctg = wid & 1;
    const short8v* Ap = (const short8v*)(Wa + (size_t)(ot * 16 + lo) * 640);
    f32x4 acc[4];
#pragma unroll
    for (int q = 0; q < 4; ++q) acc[q] = (f32x4){0.f, 0.f, 0.f, 0.f};
#pragma unroll 1
    for (int sb = 0; sb < 20; sb += 10) {
        short8v af[10];
#pragma unroll
        for (int u = 0; u < 10; ++u) af[u] = Ap[(sb + u) * 4 + kg];
#pragma unroll
        for (int u = 0; u < 10; ++u) {
            int s = sb + u;
            int kk = s >> 1, cb = s & 1;
#pragma unroll
            for (int q = 0; q < 4; ++q) {
                int r = (ctg * 4 + q) * 16 + lo + kk;
                int cs = (cb * 32 + kg * 8) ^ (8 * (r & 7));
                short8v bf = *(const short8v*)&xb[r * 64 + cs];
                acc[q] = __builtin_amdgcn_mfma_f32_16x16x32_bf16(af[u], bf, acc[q], 0, 0, 0);
            }
        }
    }
#pragma unroll
    for (int q = 0; q < 4; ++q) {
        int tloc = (ctg * 4 + q) * 16 + lo;
#pragma unroll
        for (int e = 0; e < 4; ++e) {
            int o2 = ot * 16 + kg * 4 + e;      // < 32
            float a = acc[q][e] + ws[F_B1 + o2];
            eb[o2 * 128 + tloc] = __float2bfloat16(eluf(a * ws[F_S1 + o2] + ws[F_H1 + o2]));
        }
    }
    __syncthreads();

    // pool + store [t][s][32] (4 consecutive c per 8B store; c>=25 zero)
    __hip_bfloat16* p1g = wsh + H_P1;
    for (int i = threadIdx.x; i < 8 * 42; i += 256) {
        int og = i / 42, pl = i - og * 42;
        if (pl < PTb) {
            int tp = tp0 + pl;
            unsigned short uv[4];
#pragma unroll
            for (int j = 0; j < 4; ++j) {
                int o = og * 4 + j;
                float v = 0.f;
                if (o < 25) {
                    const __hip_bfloat16* ep = eb + o * 128 + 3 * pl;
                    v = fmaxf(fmaxf(ldh(ep), ldh(ep + 1)), ldh(ep + 2));
                }
                uv[j] = bfb(v);
            }
            uint2 pk = {(unsigned)uv[0] | ((unsigned)uv[1] << 16),
                        (unsigned)uv[2] | ((unsigned)uv[3] << 16)};
            *(uint2*)(p1g + (size_t)tp * 4096 + b * 32 + og * 4) = pk;
        }
    }
}

// ---------------- K2: L2 batched GEMM (25->50) + BN + ELU + pool ----------------
// wave = (tp, 16-sample block). cols = samples, rows = out-ch. No LDS.
__global__ __launch_bounds__(256) void k_gemm2(float* __restrict__ ws) {
    __hip_bfloat16* wsh = (__hip_bfloat16*)ws;
    const __hip_bfloat16* p1 = wsh + H_P1;
    const __hip_bfloat16* W = wsh + H_WA2;
    __hip_bfloat16* p2 = wsh + H_P2;
    int w = blockIdx.x * 4 + (threadIdx.x >> 6);          // < 632 = 79*8
    int lane = threadIdx.x & 63, lo = lane & 15, kg = lane >> 4;
    int tp = w >> 3, s0 = (w & 7) * 16;

    const __hip_bfloat16* bbase = p1 + (size_t)(s0 + lo) * 32 + kg * 8;
    short8v B[12];
#pragma unroll
    for (int v = 0; v < 12; ++v)
        B[v] = *(const short8v*)(bbase + (size_t)(3 * tp + v) * 4096);

    f32x4 acc[4][3];
#pragma unroll
    for (int ot = 0; ot < 4; ++ot)
#pragma unroll
        for (int u = 0; u < 3; ++u) acc[ot][u] = (f32x4){0.f, 0.f, 0.f, 0.f};

#pragma unroll
    for (int ot = 0; ot < 4; ++ot) {
        const __hip_bfloat16* arow = W + (size_t)(ot * 16 + lo) * 320 + kg * 8;
#pragma unroll
        for (int kk = 0; kk < 10; ++kk) {
            short8v a = *(const short8v*)(arow + kk * 32);
#pragma unroll
            for (int u = 0; u < 3; ++u)
                acc[ot][u] = __builtin_amdgcn_mfma_f32_16x16x32_bf16(a, B[kk + u], acc[ot][u], 0, 0, 0);
        }
    }

    __hip_bfloat16* obase = p2 + (size_t)(tp * 128 + s0 + lo) * 64;
#pragma unroll
    for (int ot = 0; ot < 4; ++ot) {
        unsigned short uv[4];
#pragma unroll
        for (int e = 0; e < 4; ++e) {
            int o2 = ot * 16 + kg * 4 + e;
            float m = fmaxf(fmaxf(acc[ot][0][e], acc[ot][1][e]), acc[ot][2][e]);
            float val = (o2 < 50) ? eluf(m * ws[F_S2 + o2] + ws[F_H2 + o2]) : 0.f;
            uv[e] = bfb(val);
        }
        uint2 pk = {(unsigned)uv[0] | ((unsigned)uv[1] << 16),
                    (unsigned)uv[2] | ((unsigned)uv[3] << 16)};
        *(uint2*)(obase + ot * 16 + kg * 4) = pk;
    }
}

// ---------------- K3: L3 batched GEMM (50->100) ----------------
__global__ __launch_bounds__(256) void k_gemm3(float* __restrict__ ws) {
    __hip_bfloat16* wsh = (__hip_bfloat16*)ws;
    const __hip_bfloat16* p2 = wsh + H_P2;
    const __hip_bfloat16* W = wsh + H_WA3;
    __hip_bfloat16* p3 = wsh + H_P3;
    int w = blockIdx.x * 4 + (threadIdx.x >> 6);          // < 368 = 23*8*2
    int lane = threadIdx.x & 63, lo = lane & 15, kg = lane >> 4;
    int col = w >> 1, oz = w & 1;
    int tp = col >> 3, s0 = (col & 7) * 16;

    const __hip_bfloat16* bbase = p2 + (size_t)(s0 + lo) * 64 + kg * 8;
    f32x4 acc[4][3];
#pragma unroll
    for (int ot = 0; ot < 4; ++ot)
#pragma unroll
        for (int u = 0; u < 3; ++u) acc[ot][u] = (f32x4){0.f, 0.f, 0.f, 0.f};

#pragma unroll
    for (int cb = 0; cb < 2; ++cb) {
        short8v B[12];
#pragma unroll
        for (int v = 0; v < 12; ++v)
            B[v] = *(const short8v*)(bbase + (size_t)(3 * tp + v) * 8192 + cb * 32);
#pragma unroll
        for (int ot = 0; ot < 4; ++ot) {
            if (oz && ot == 3) continue;                  // only 7 real o-tiles
            const __hip_bfloat16* arow =
                W + (size_t)(oz * 64 + ot * 16 + lo) * 640 + cb * 32 + kg * 8;
#pragma unroll
            for (int kk = 0; kk < 10; ++kk) {
                short8v a = *(const short8v*)(arow + kk * 64);
#pragma unroll
                for (int u = 0; u < 3; ++u)
                    acc[ot][u] = __builtin_amdgcn_mfma_f32_16x16x32_bf16(a, B[kk + u], acc[ot][u], 0, 0, 0);
            }
        }
    }

    __hip_bfloat16* obase = p3 + (size_t)(tp * 128 + s0 + lo) * 128;
#pragma unroll
    for (int ot = 0; ot < 4; ++ot) {
        unsigned short uv[4];
#pragma unroll
        for (int e = 0; e < 4; ++e) {
            int o2 = oz * 64 + ot * 16 + kg * 4 + e;
            float val = 0.f;
            if (o2 < 100) {
                float m = fmaxf(fmaxf(acc[ot][0][e], acc[ot][1][e]), acc[ot][2][e]);
                val = eluf(m * ws[F_S3 + o2] + ws[F_H3 + o2]);
            }
            uv[e] = bfb(val);
        }
        uint2 pk = {(unsigned)uv[0] | ((unsigned)uv[1] << 16),
                    (unsigned)uv[2] | ((unsigned)uv[3] << 16)};
        *(uint2*)(obase + oz * 64 + ot * 16 + kg * 4) = pk;
    }
}

// ---------------- K4: L4 batched GEMM (100->200), fp32 out [s][o][4] ----------------
__global__ __launch_bounds__(256) void k_gemm4(float* __restrict__ ws) {
    __hip_bfloat16* wsh = (__hip_bfloat16*)ws;
    const __hip_bfloat16* p3 = wsh + H_P3;
    const __hip_bfloat16* W = wsh + H_WA4;
    float* p4 = ws + F_P4;
    int w = blockIdx.x * 4 + (threadIdx.x >> 6);          // < 416 = 32*13
    int lane = threadIdx.x & 63, lo = lane & 15, kg = lane >> 4;
    int ot = w >> 5, ct = w & 31;
    int tp = ct >> 3, s0 = (ct & 7) * 16;

    const __hip_bfloat16* bbase = p3 + (size_t)(s0 + lo) * 128 + kg * 8;
    const __hip_bfloat16* arow0 = W + (size_t)(ot * 16 + lo) * 1280 + kg * 8;
    f32x4 acc[3];
#pragma unroll
    for (int u = 0; u < 3; ++u) acc[u] = (f32x4){0.f, 0.f, 0.f, 0.f};

#pragma unroll
    for (int cb = 0; cb < 4; ++cb) {
        short8v B[12];
#pragma unroll
        for (int v = 0; v < 12; ++v)
            B[v] = *(const short8v*)(bbase + (size_t)(3 * tp + v) * 16384 + cb * 32);
        const __hip_bfloat16* arow = arow0 + cb * 32;
#pragma unroll
        for (int kk = 0; kk < 10; ++kk) {
            short8v a = *(const short8v*)(arow + kk * 128);
#pragma unroll
            for (int u = 0; u < 3; ++u)
                acc[u] = __builtin_amdgcn_mfma_f32_16x16x32_bf16(a, B[kk + u], acc[u], 0, 0, 0);
        }
    }

#pragma unroll
    for (int e = 0; e < 4; ++e) {
        int o2 = ot * 16 + kg * 4 + e;
        if (o2 < 200) {
            float m = fmaxf(fmaxf(acc[0][e], acc[1][e]), acc[2][e]);
            p4[((size_t)(s0 + lo) * 200 + o2) * 4 + tp] =
                eluf(m * ws[F_S4 + o2] + ws[F_H4 + o2]);
        }
    }
}

// ---------------- K5: fc conv + per-sample MoE heads ----------------
__global__ __launch_bounds__(128) void k_heads(
    const float* __restrict__ ws,
    const float* __restrict__ fcw, const float* __restrict__ fcb,
    const int* __restrict__ cids,
    const float* __restrict__ hW1, const float* __restrict__ hb1,
    const float* __restrict__ hW2, const float* __restrict__ hb2,
    float* __restrict__ out) {
    const float* p4 = ws + F_P4;
    __shared__ float red[4][128];
    __shared__ float fs[4];
    int b = blockIdx.x, j = threadIdx.x;

    float pa[4] = {0.f, 0.f, 0.f, 0.f};
    for (int c = j; c < 200; c += 128) {
        const float* pp = p4 + ((size_t)b * 200 + c) * 4;
        float v0 = pp[0], v1 = pp[1], v2 = pp[2], v3 = pp[3];
#pragma unroll
        for (int o = 0; o < 4; ++o) {
            const float* fw = fcw + (o * 200 + c) * 4;
            pa[o] += fw[0] * v0 + fw[1] * v1 + fw[2] * v2 + fw[3] * v3;
        }
    }
#pragma unroll
    for (int o = 0; o < 4; ++o) red[o][j] = pa[o];
    __syncthreads();
    for (int s = 64; s > 0; s >>= 1) {
        if (j < s) {
#pragma unroll
            for (int o = 0; o < 4; ++o) red[o][j] += red[o][j + s];
        }
        __syncthreads();
    }
    if (j < 4) fs[j] = red[j][0] + fcb[j];
    __syncthreads();

    int cid = cids[b];
    float hvv = hb1[cid * 128 + j];
#pragma unroll
    for (int f = 0; f < 4; ++f) hvv += fs[f] * hW1[(cid * 4 + f) * 128 + j];
    hvv = fmaxf(hvv, 0.f);
#pragma unroll
    for (int o = 0; o < 4; ++o) red[o][j] = hvv * hW2[(cid * 128 + j) * 4 + o];
    __syncthreads();
    for (int s = 64; s > 0; s >>= 1) {
        if (j < s) {
#pragma unroll
            for (int o = 0; o < 4; ++o) red[o][j] += red[o][j + s];
        }
        __syncthreads();
    }
    if (j < 4) out[b * 4 + j] = red[j][0] + hb2[cid * 4 + j];
}

// ---------------- launch ----------------
extern "C" void kernel_launch(void* const* d_in, const int* in_sizes, int n_in,
                              void* d_out, int out_size, void* d_ws, size_t ws_size,
                              hipStream_t stream) {
    (void)in_sizes; (void)n_in; (void)out_size; (void)ws_size;
    const float* x    = (const float*)d_in[0];
    const int*   cid  = (const int*)d_in[1];
    const float* ctw  = (const float*)d_in[2];
    const float* ctb  = (const float*)d_in[3];
    const float* csw  = (const float*)d_in[4];
    const float* g1 = (const float*)d_in[5],  *b1 = (const float*)d_in[6];
    const float* m1 = (const float*)d_in[7],  *v1 = (const float*)d_in[8];
    const float* w2 = (const float*)d_in[9];
    const float* g2 = (const float*)d_in[10], *b2 = (const float*)d_in[11];
    const float* m2 = (const float*)d_in[12], *v2 = (const float*)d_in[13];
    const float* w3 = (const float*)d_in[14];
    const float* g3 = (const float*)d_in[15], *b3 = (const float*)d_in[16];
    const float* m3 = (const float*)d_in[17], *v3 = (const float*)d_in[18];
    const float* w4 = (const float*)d_in[19];
    const float* g4 = (const float*)d_in[20], *b4 = (const float*)d_in[21];
    const float* m4 = (const float*)d_in[22], *v4 = (const float*)d_in[23];
    const float* fcw = (const float*)d_in[24], *fcb = (const float*)d_in[25];
    const float* hW1 = (const float*)d_in[26], *hb1 = (const float*)d_in[27];
    const float* hW2 = (const float*)d_in[28], *hb2 = (const float*)d_in[29];
    float* ws  = (float*)d_ws;
    float* out = (float*)d_out;

    k_pre2<<<dim3((N_WTOT + 512 + 255) / 256), dim3(256), 0, stream>>>(
        ctw, ctb, csw, g1, b1, m1, v1, w2, g2, b2, m2, v2,
        w3, g3, b3, m3, v3, w4, g4, b4, m4, v4, ws);
    k_conv1<<<dim3(6, 128), dim3(256), 0, stream>>>(x, ws);
    k_gemm2<<<dim3(158), dim3(256), 0, stream>>>(ws);   // 632 waves
    k_gemm3<<<dim3(92),  dim3(256), 0, stream>>>(ws);   // 368 waves
    k_gemm4<<<dim3(104), dim3(256), 0, stream>>>(ws);   // 416 waves
    k_heads<<<dim3(128), dim3(128), 0, stream>>>(ws, fcw, fcb, cid,
                                                 hW1, hb1, hW2, hb2, out);
}